// Round 7
// baseline (89.631 us; speedup 1.0000x reference)
//
#include <hip/hip_runtime.h>

// out[b,m,p] (B=512, OUT=400):
//   = x[b,m,p]   for m<256 && p<256   (eye = identity embedding)
//   = 1.0f       for m==p >= 256      (add = diag(0*256, 1*144))
//   = 0.0f       otherwise
// Lane-contiguous NT accesses; 8 f4 per thread via WAVE-STRIDE unroll
// (block*2048 + j*256 + tid): every instruction = contiguous 1KB wave access,
// 8 independent loads in flight -> 8KB same-direction HBM bursts.
// Traffic: 134.2MB read + 327.7MB write (no amplification).

typedef float f32x4 __attribute__((ext_vector_type(4)));

constexpr unsigned B   = 512;
constexpr unsigned IN  = 256;
constexpr unsigned OUT = 400;
constexpr unsigned ROW4     = OUT / 4;             // 100 f4 per out row
constexpr unsigned TOTAL_F4 = B * OUT * ROW4;      // 20,480,000 = 10000*2048
constexpr unsigned J        = 8;                   // f4 per thread
constexpr unsigned PER_BLK  = 256 * J;             // 2048

__global__ __launch_bounds__(256) void spd_unroll8(
    const f32x4* __restrict__ x4, f32x4* __restrict__ out4)
{
    const unsigned base = blockIdx.x * PER_BLK + threadIdx.x;

    f32x4 v[J];                       // fully unrolled, static indices only
#pragma unroll
    for (unsigned j = 0; j < J; ++j) {
        const unsigned i = base + j * 256u;
        unsigned bm = i / 100u;       // magic mulhi
        unsigned p4 = i - bm * 100u;
        unsigned b  = bm / 400u;      // magic mulhi
        unsigned m  = bm - b * 400u;

        if (m < IN && p4 < (IN / 4)) {
            v[j] = __builtin_nontemporal_load(&x4[(b << 14) + (m << 6) + p4]);
        } else {
            f32x4 z = (f32x4){0.f, 0.f, 0.f, 0.f};
            if (m >= IN && p4 == (m >> 2)) {
                z[m & 3u] = 1.0f;     // diagonal one from `add`
            }
            v[j] = z;
        }
    }

#pragma unroll
    for (unsigned j = 0; j < J; ++j) {
        __builtin_nontemporal_store(v[j], &out4[base + j * 256u]);
    }
}

extern "C" void kernel_launch(void* const* d_in, const int* in_sizes, int n_in,
                              void* d_out, int out_size, void* d_ws, size_t ws_size,
                              hipStream_t stream)
{
    const f32x4* x4 = (const f32x4*)d_in[0];  // [B, IN, IN]
    f32x4* out4 = (f32x4*)d_out;              // [B, OUT, OUT]

    spd_unroll8<<<TOTAL_F4 / PER_BLK, 256, 0, stream>>>(x4, out4);
}

// Round 8
// 85.103 us; speedup vs baseline: 1.0532x; 1.0532x over previous
//
#include <hip/hip_runtime.h>

// out[b,m,p] (B=512, OUT=400):
//   = x[b,m,p]   for m<256 && p<256   (eye = identity embedding)
//   = 1.0f       for m==p >= 256      (add = diag(0*256, 1*144))
//   = 0.0f       otherwise
// Lane-contiguous (coalesced) NT accesses; 4 f4 per thread via WAVE-STRIDE
// unroll (block*1024 + j*256 + tid): every instruction is a contiguous 1KB
// wave access, 4 independent loads in flight per thread.
// Probed J=1 (87.2us), J=4 (85.3us), J=8 (89.6us) -> J=4 optimal.
// Traffic: 134.2MB read + 327.7MB write (counters: no amplification).
// 462MB / 85.3us = 5.42 TB/s = ~86% of 6.3 TB/s achievable -> at roofline.

typedef float f32x4 __attribute__((ext_vector_type(4)));

constexpr unsigned B   = 512;
constexpr unsigned IN  = 256;
constexpr unsigned OUT = 400;
constexpr unsigned ROW4     = OUT / 4;             // 100 f4 per out row
constexpr unsigned TOTAL_F4 = B * OUT * ROW4;      // 20,480,000 = 20000*1024
constexpr unsigned PER_BLK  = 1024;                // 256 threads x 4 f4

__global__ __launch_bounds__(256) void spd_unroll4(
    const f32x4* __restrict__ x4, f32x4* __restrict__ out4)
{
    const unsigned base = blockIdx.x * PER_BLK + threadIdx.x;

    f32x4 v0, v1, v2, v3;   // static names, stays in VGPRs
#pragma unroll
    for (unsigned j = 0; j < 4; ++j) {
        const unsigned i = base + j * 256u;
        unsigned bm = i / 100u;              // magic mulhi
        unsigned p4 = i - bm * 100u;
        unsigned b  = bm / 400u;             // magic mulhi
        unsigned m  = bm - b * 400u;

        f32x4 v;
        if (m < IN && p4 < (IN / 4)) {
            v = __builtin_nontemporal_load(&x4[(b << 14) + (m << 6) + p4]);
        } else {
            v = (f32x4){0.f, 0.f, 0.f, 0.f};
            if (m >= IN && p4 == (m >> 2)) {
                v[m & 3u] = 1.0f;            // diagonal one from `add`
            }
        }
        if (j == 0) v0 = v; else if (j == 1) v1 = v;
        else if (j == 2) v2 = v; else v3 = v;
    }

    __builtin_nontemporal_store(v0, &out4[base + 0u * 256u]);
    __builtin_nontemporal_store(v1, &out4[base + 1u * 256u]);
    __builtin_nontemporal_store(v2, &out4[base + 2u * 256u]);
    __builtin_nontemporal_store(v3, &out4[base + 3u * 256u]);
}

extern "C" void kernel_launch(void* const* d_in, const int* in_sizes, int n_in,
                              void* d_out, int out_size, void* d_ws, size_t ws_size,
                              hipStream_t stream)
{
    const f32x4* x4 = (const f32x4*)d_in[0];  // [B, IN, IN]
    f32x4* out4 = (f32x4*)d_out;              // [B, OUT, OUT]

    spd_unroll4<<<TOTAL_F4 / PER_BLK, 256, 0, stream>>>(x4, out4);
}